// Round 1
// baseline (512.946 us; speedup 1.0000x reference)
//
#include <hip/hip_runtime.h>

#define D0 232
#define MED 1024
#define HID 256
#define TDIM 768
#define NTRAIN 4096

#define BM 64
#define BN 64
#define BK 16

// C[M,N] = (A1 * rowScale) @ W1^T  [+ A2 @ W2^T]  + bias, optional relu.
// A1 rows optionally gathered via `gather`. W is (N,K) row-major (so @ W^T).
__global__ __launch_bounds__(256) void gemm_fused(
    const float* __restrict__ A1, int lda1,
    const int* __restrict__ gather,
    const float* __restrict__ rowScale,
    const float* __restrict__ W1,
    const float* __restrict__ A2,          // optional second operand, lda = K
    const float* __restrict__ W2,
    const float* __restrict__ bias,
    float* __restrict__ C,
    int M, int N, int K, int doRelu)
{
    __shared__ float As[BK][BM + 4];
    __shared__ float Bs[BK][BN + 4];

    const int tid  = threadIdx.x;
    const int tx   = tid & 15;
    const int ty   = tid >> 4;
    const int row0 = blockIdx.y * BM;
    const int col0 = blockIdx.x * BN;

    const int lrow = tid >> 2;        // 0..63: A-row / W-row within tile
    const int kb   = (tid & 3) * 4;   // 0,4,8,12

    float acc[4][4] = {};

    for (int pass = 0; pass < 2; ++pass) {
        const float* __restrict__ A = pass ? A2 : A1;
        const float* __restrict__ W = pass ? W2 : W1;
        if (A == nullptr) break;
        const int lda = pass ? K : lda1;
        const bool useGather = (pass == 0) && (gather != nullptr);
        const bool useScale  = (pass == 0) && (rowScale != nullptr);

        const int arow = row0 + lrow;           // M is a multiple of 64 here
        const int ridx = useGather ? gather[arow] : arow;
        const long abase = (long)ridx * lda;
        const float scale = useScale ? rowScale[arow] : 1.0f;

        const int  brow   = col0 + lrow;        // output column index
        const bool bvalid = brow < N;
        const long bbase  = (long)(bvalid ? brow : 0) * K;

        for (int k0 = 0; k0 < K; k0 += BK) {
            const int kk = k0 + kb;
            if (kk + 3 < K) {
                float4 av = *reinterpret_cast<const float4*>(&A[abase + kk]);
                As[kb + 0][lrow] = av.x * scale;
                As[kb + 1][lrow] = av.y * scale;
                As[kb + 2][lrow] = av.z * scale;
                As[kb + 3][lrow] = av.w * scale;
                if (bvalid) {
                    float4 bv = *reinterpret_cast<const float4*>(&W[bbase + kk]);
                    Bs[kb + 0][lrow] = bv.x;
                    Bs[kb + 1][lrow] = bv.y;
                    Bs[kb + 2][lrow] = bv.z;
                    Bs[kb + 3][lrow] = bv.w;
                } else {
                    Bs[kb + 0][lrow] = 0.f; Bs[kb + 1][lrow] = 0.f;
                    Bs[kb + 2][lrow] = 0.f; Bs[kb + 3][lrow] = 0.f;
                }
            } else {
                #pragma unroll
                for (int i = 0; i < 4; ++i) {
                    int k = kk + i;
                    As[kb + i][lrow] = (k < K) ? A[abase + k] * scale : 0.0f;
                    Bs[kb + i][lrow] = (bvalid && k < K) ? W[bbase + k] : 0.0f;
                }
            }
            __syncthreads();
            #pragma unroll
            for (int k = 0; k < BK; ++k) {
                float4 a = *reinterpret_cast<const float4*>(&As[k][ty * 4]);
                float4 b = *reinterpret_cast<const float4*>(&Bs[k][tx * 4]);
                float av[4] = {a.x, a.y, a.z, a.w};
                float bv[4] = {b.x, b.y, b.z, b.w};
                #pragma unroll
                for (int i = 0; i < 4; ++i)
                    #pragma unroll
                    for (int j = 0; j < 4; ++j)
                        acc[i][j] += av[i] * bv[j];
            }
            __syncthreads();
        }
    }

    #pragma unroll
    for (int i = 0; i < 4; ++i) {
        int r = row0 + ty * 4 + i;
        if (r >= M) continue;
        #pragma unroll
        for (int j = 0; j < 4; ++j) {
            int c = col0 + tx * 4 + j;
            if (c >= N) continue;
            float v = acc[i][j] + bias[c];
            if (doRelu) v = fmaxf(v, 0.0f);
            C[(long)r * N + c] = v;
        }
    }
}

__global__ void deg_count(const int* __restrict__ dst, float* __restrict__ deg, int E)
{
    int e = blockIdx.x * blockDim.x + threadIdx.x;
    if (e < E) atomicAdd(&deg[dst[e]], 1.0f);
}

__global__ void deg_inv(float* __restrict__ deg, int n)
{
    int i = blockIdx.x * blockDim.x + threadIdx.x;
    if (i < n) deg[i] = 1.0f / fmaxf(deg[i], 1.0f);
}

// One block per edge: agg[dst] += x[src]  (fp32 atomics, agg is L2-resident)
__global__ __launch_bounds__(256) void edge_agg(
    const int* __restrict__ src, const int* __restrict__ dst,
    const float* __restrict__ x, float* __restrict__ agg, int E, int D)
{
    int e = blockIdx.x;
    if (e >= E) return;
    const int s = src[e];
    const int d = dst[e];
    const float* xs = x + (long)s * D;
    float* ad = agg + (long)d * D;
    for (int f = threadIdx.x; f < D; f += 256)
        atomicAdd(&ad[f], xs[f]);
}

// out[i,c] = sum_d x2[model_ids[i],d] * q[i,d] * cls_W[c,d] + cls_b[c]
__global__ __launch_bounds__(256) void final_head(
    const float* __restrict__ x2, const float* __restrict__ q,
    const int* __restrict__ model_ids,
    const float* __restrict__ cls_W, const float* __restrict__ cls_b,
    float* __restrict__ out, int B)
{
    int w    = (blockIdx.x * blockDim.x + threadIdx.x) >> 6;
    int lane = threadIdx.x & 63;
    if (w >= B) return;
    const float* p  = x2 + (long)model_ids[w] * D0;
    const float* qr = q + (long)w * D0;
    float s0 = 0.f, s1 = 0.f;
    for (int d = lane; d < D0; d += 64) {
        float v = p[d] * qr[d];
        s0 += v * cls_W[d];
        s1 += v * cls_W[D0 + d];
    }
    #pragma unroll
    for (int off = 32; off > 0; off >>= 1) {
        s0 += __shfl_down(s0, off);
        s1 += __shfl_down(s1, off);
    }
    if (lane == 0) {
        out[(long)w * 2 + 0] = s0 + cls_b[0];
        out[(long)w * 2 + 1] = s1 + cls_b[1];
    }
}

extern "C" void kernel_launch(void* const* d_in, const int* in_sizes, int n_in,
                              void* d_out, int out_size, void* d_ws, size_t ws_size,
                              hipStream_t stream)
{
    const float* P_weight     = (const float*)d_in[0];
    const float* model_proj_W = (const float*)d_in[1];
    const float* model_proj_b = (const float*)d_in[2];
    const float* sage1_Wl     = (const float*)d_in[3];
    const float* sage1_bl     = (const float*)d_in[4];
    const float* sage1_Wr     = (const float*)d_in[5];
    const float* sage2_Wl     = (const float*)d_in[6];
    const float* sage2_bl     = (const float*)d_in[7];
    const float* sage2_Wr     = (const float*)d_in[8];
    const float* Q_weight     = (const float*)d_in[9];
    const float* text_proj_W  = (const float*)d_in[10];
    const float* text_proj_b  = (const float*)d_in[11];
    const float* cls_W        = (const float*)d_in[12];
    const float* cls_b        = (const float*)d_in[13];
    const int*   edge_index   = (const int*)d_in[14];
    const int*   model_ids    = (const int*)d_in[15];
    const int*   prompt_ids   = (const int*)d_in[16];

    const int E = in_sizes[14] / 2;
    const int B = in_sizes[15];
    const int* src = edge_index;
    const int* dst = edge_index + E;

    float* ws  = (float*)d_ws;
    float* x0  = ws;                        // 4096*232
    float* h1  = x0 + NTRAIN * D0;          // 4096*256
    float* x2  = h1 + NTRAIN * HID;         // 4096*232
    float* agg = x2 + NTRAIN * D0;          // 4096*256 (reused both layers)
    float* deg = agg + NTRAIN * HID;        // 4096 (becomes inv-degree)
    float* q   = deg + NTRAIN;              // B*232

    dim3 blk(256);

    // degree -> inverse degree
    hipMemsetAsync(deg, 0, NTRAIN * sizeof(float), stream);
    deg_count<<<(E + 255) / 256, blk, 0, stream>>>(dst, deg, E);
    deg_inv<<<(NTRAIN + 255) / 256, blk, 0, stream>>>(deg, NTRAIN);

    // x0 = P_weight[:4096] @ model_proj_W^T + b
    gemm_fused<<<dim3((D0 + BN - 1) / BN, NTRAIN / BM), blk, 0, stream>>>(
        P_weight, MED, nullptr, nullptr, model_proj_W,
        nullptr, nullptr, model_proj_b, x0, NTRAIN, D0, MED, 0);

    // layer-1 aggregation
    hipMemsetAsync(agg, 0, (size_t)NTRAIN * D0 * sizeof(float), stream);
    edge_agg<<<E, blk, 0, stream>>>(src, dst, x0, agg, E, D0);

    // h1 = relu((agg*invdeg) @ W1l^T + b1 + x0 @ W1r^T)
    gemm_fused<<<dim3((HID + BN - 1) / BN, NTRAIN / BM), blk, 0, stream>>>(
        agg, D0, nullptr, deg, sage1_Wl,
        x0, sage1_Wr, sage1_bl, h1, NTRAIN, HID, D0, 1);

    // layer-2 aggregation
    hipMemsetAsync(agg, 0, (size_t)NTRAIN * HID * sizeof(float), stream);
    edge_agg<<<E, blk, 0, stream>>>(src, dst, h1, agg, E, HID);

    // x2 = (agg*invdeg) @ W2l^T + b2 + h1 @ W2r^T
    gemm_fused<<<dim3((D0 + BN - 1) / BN, NTRAIN / BM), blk, 0, stream>>>(
        agg, HID, nullptr, deg, sage2_Wl,
        h1, sage2_Wr, sage2_bl, x2, NTRAIN, D0, HID, 0);

    // q = Q_weight[prompt_ids] @ text_proj_W^T + b
    gemm_fused<<<dim3((D0 + BN - 1) / BN, B / BM), blk, 0, stream>>>(
        Q_weight, TDIM, prompt_ids, nullptr, text_proj_W,
        nullptr, nullptr, text_proj_b, q, B, D0, TDIM, 0);

    // head
    final_head<<<(B * 64 + 255) / 256, blk, 0, stream>>>(
        x2, q, model_ids, cls_W, cls_b, (float*)d_out, B);
}

// Round 2
// 350.323 us; speedup vs baseline: 1.4642x; 1.4642x over previous
//
#include <hip/hip_runtime.h>

#define D0 232
#define MED 1024
#define HID 256
#define TDIM 768
#define NTRAIN 4096

#define BM 64
#define BN 64
#define BK 16

// C (+)= (gathered A1) @ W1^T [+ A2 @ W2^T] (+ bias once, z==0), atomic when gridDim.z>1.
// W is (N,K) row-major. Split-K via blockIdx.z with chunk Kc.
__global__ __launch_bounds__(256) void gemm_fused(
    const float* __restrict__ A1, int lda1,
    const int* __restrict__ gather,
    const float* __restrict__ W1,
    const float* __restrict__ A2,          // optional second operand, lda = K
    const float* __restrict__ W2,
    const float* __restrict__ bias,
    float* __restrict__ C,
    int M, int N, int K, int Kc)
{
    __shared__ float As[BK][BM + 4];
    __shared__ float Bs[BK][BN + 4];

    const int tid  = threadIdx.x;
    const int tx   = tid & 15;
    const int ty   = tid >> 4;
    const int row0 = blockIdx.y * BM;
    const int col0 = blockIdx.x * BN;
    const int kbeg = blockIdx.z * Kc;
    const int kend = min(K, kbeg + Kc);

    const int lrow = tid >> 2;        // 0..63
    const int kb   = (tid & 3) * 4;   // 0,4,8,12

    float acc[4][4] = {};

    for (int pass = 0; pass < 2; ++pass) {
        const float* __restrict__ A = pass ? A2 : A1;
        const float* __restrict__ W = pass ? W2 : W1;
        if (A == nullptr) break;
        const int lda = pass ? K : lda1;
        const bool useGather = (pass == 0) && (gather != nullptr);

        const int arow = row0 + lrow;           // M is a multiple of 64
        const int ridx = useGather ? gather[arow] : arow;
        const long abase = (long)ridx * lda;

        const int  brow   = col0 + lrow;        // output column index
        const bool bvalid = brow < N;
        const long bbase  = (long)(bvalid ? brow : 0) * K;

        for (int k0 = kbeg; k0 < kend; k0 += BK) {
            const int kk = k0 + kb;
            if (kk + 3 < kend) {
                float4 av = *reinterpret_cast<const float4*>(&A[abase + kk]);
                As[kb + 0][lrow] = av.x;
                As[kb + 1][lrow] = av.y;
                As[kb + 2][lrow] = av.z;
                As[kb + 3][lrow] = av.w;
                if (bvalid) {
                    float4 bv = *reinterpret_cast<const float4*>(&W[bbase + kk]);
                    Bs[kb + 0][lrow] = bv.x;
                    Bs[kb + 1][lrow] = bv.y;
                    Bs[kb + 2][lrow] = bv.z;
                    Bs[kb + 3][lrow] = bv.w;
                } else {
                    Bs[kb + 0][lrow] = 0.f; Bs[kb + 1][lrow] = 0.f;
                    Bs[kb + 2][lrow] = 0.f; Bs[kb + 3][lrow] = 0.f;
                }
            } else {
                #pragma unroll
                for (int i = 0; i < 4; ++i) {
                    int k = kk + i;
                    As[kb + i][lrow] = (k < kend) ? A[abase + k] : 0.0f;
                    Bs[kb + i][lrow] = (bvalid && k < kend) ? W[bbase + k] : 0.0f;
                }
            }
            __syncthreads();
            #pragma unroll
            for (int k = 0; k < BK; ++k) {
                float4 a = *reinterpret_cast<const float4*>(&As[k][ty * 4]);
                float4 b = *reinterpret_cast<const float4*>(&Bs[k][tx * 4]);
                float av[4] = {a.x, a.y, a.z, a.w};
                float bv[4] = {b.x, b.y, b.z, b.w};
                #pragma unroll
                for (int i = 0; i < 4; ++i)
                    #pragma unroll
                    for (int j = 0; j < 4; ++j)
                        acc[i][j] += av[i] * bv[j];
            }
            __syncthreads();
        }
    }

    const bool addB = (bias != nullptr) && (blockIdx.z == 0);
    const bool direct = (gridDim.z == 1);
    #pragma unroll
    for (int i = 0; i < 4; ++i) {
        int r = row0 + ty * 4 + i;
        if (r >= M) continue;
        #pragma unroll
        for (int j = 0; j < 4; ++j) {
            int c = col0 + tx * 4 + j;
            if (c >= N) continue;
            float v = acc[i][j];
            if (addB) v += bias[c];
            if (direct) C[(long)r * N + c] = v;
            else        atomicAdd(&C[(long)r * N + c], v);
        }
    }
}

__global__ void hist_kernel(const int* __restrict__ dst, int* __restrict__ hist, int E)
{
    int e = blockIdx.x * blockDim.x + threadIdx.x;
    if (e < E) atomicAdd(&hist[dst[e]], 1);
}

// 4096-entry exclusive scan in one 1024-thread block; also invdeg = 1/max(cnt,1)
__global__ __launch_bounds__(1024) void scan_kernel(
    const int* __restrict__ hist, int* __restrict__ row_ptr,
    float* __restrict__ invdeg, int E)
{
    __shared__ int s[1024];
    const int t = threadIdx.x;
    int4 c = reinterpret_cast<const int4*>(hist)[t];
    int local = c.x + c.y + c.z + c.w;
    s[t] = local;
    __syncthreads();
    for (int off = 1; off < 1024; off <<= 1) {
        int v = (t >= off) ? s[t - off] : 0;
        __syncthreads();
        s[t] += v;
        __syncthreads();
    }
    int base = s[t] - local;                 // exclusive
    row_ptr[4 * t + 0] = base;
    row_ptr[4 * t + 1] = base + c.x;
    row_ptr[4 * t + 2] = base + c.x + c.y;
    row_ptr[4 * t + 3] = base + c.x + c.y + c.z;
    if (t == 1023) row_ptr[4096] = E;
    invdeg[4 * t + 0] = 1.0f / fmaxf((float)c.x, 1.0f);
    invdeg[4 * t + 1] = 1.0f / fmaxf((float)c.y, 1.0f);
    invdeg[4 * t + 2] = 1.0f / fmaxf((float)c.z, 1.0f);
    invdeg[4 * t + 3] = 1.0f / fmaxf((float)c.w, 1.0f);
}

__global__ void scatter_kernel(
    const int* __restrict__ src, const int* __restrict__ dst,
    const int* __restrict__ row_ptr, int* __restrict__ cursor,
    int* __restrict__ csr, int E)
{
    int e = blockIdx.x * blockDim.x + threadIdx.x;
    if (e >= E) return;
    int d = dst[e];
    int pos = atomicAdd(&cursor[d], 1);
    csr[row_ptr[d] + pos] = src[e];
}

// One block per destination node: agg[i] = invdeg[i] * sum_{s in N(i)} x[s]
__global__ __launch_bounds__(256) void node_agg(
    const int* __restrict__ row_ptr, const int* __restrict__ csr,
    const float* __restrict__ invdeg,
    const float* __restrict__ x, float* __restrict__ agg, int D)
{
    __shared__ int nb[256];
    const int i = blockIdx.x;
    const int t = threadIdx.x;
    const int beg = row_ptr[i], end = row_ptr[i + 1];
    float a0 = 0.f, a1 = 0.f, a2 = 0.f, a3 = 0.f;
    for (int base = beg; base < end; base += 256) {
        int n = min(256, end - base);
        if (t < n) nb[t] = csr[base + t];
        __syncthreads();
        if (t < D) {
            int j = 0;
            for (; j + 3 < n; j += 4) {
                a0 += x[(long)nb[j + 0] * D + t];
                a1 += x[(long)nb[j + 1] * D + t];
                a2 += x[(long)nb[j + 2] * D + t];
                a3 += x[(long)nb[j + 3] * D + t];
            }
            for (; j < n; ++j) a0 += x[(long)nb[j] * D + t];
        }
        __syncthreads();
    }
    if (t < D) agg[(long)i * D + t] = (a0 + a1 + a2 + a3) * invdeg[i];
}

__global__ void relu_kernel(float* __restrict__ p, int n)
{
    int i = blockIdx.x * blockDim.x + threadIdx.x;
    if (i < n) p[i] = fmaxf(p[i], 0.0f);
}

// out[i,c] = sum_d x2[model_ids[i],d] * q[i,d] * cls_W[c,d] + cls_b[c]
__global__ __launch_bounds__(256) void final_head(
    const float* __restrict__ x2, const float* __restrict__ q,
    const int* __restrict__ model_ids,
    const float* __restrict__ cls_W, const float* __restrict__ cls_b,
    float* __restrict__ out, int B)
{
    int w    = (blockIdx.x * blockDim.x + threadIdx.x) >> 6;
    int lane = threadIdx.x & 63;
    if (w >= B) return;
    const float* p  = x2 + (long)model_ids[w] * D0;
    const float* qr = q + (long)w * D0;
    float s0 = 0.f, s1 = 0.f;
    for (int d = lane; d < D0; d += 64) {
        float v = p[d] * qr[d];
        s0 += v * cls_W[d];
        s1 += v * cls_W[D0 + d];
    }
    #pragma unroll
    for (int off = 32; off > 0; off >>= 1) {
        s0 += __shfl_down(s0, off);
        s1 += __shfl_down(s1, off);
    }
    if (lane == 0) {
        out[(long)w * 2 + 0] = s0 + cls_b[0];
        out[(long)w * 2 + 1] = s1 + cls_b[1];
    }
}

extern "C" void kernel_launch(void* const* d_in, const int* in_sizes, int n_in,
                              void* d_out, int out_size, void* d_ws, size_t ws_size,
                              hipStream_t stream)
{
    const float* P_weight     = (const float*)d_in[0];
    const float* model_proj_W = (const float*)d_in[1];
    const float* model_proj_b = (const float*)d_in[2];
    const float* sage1_Wl     = (const float*)d_in[3];
    const float* sage1_bl     = (const float*)d_in[4];
    const float* sage1_Wr     = (const float*)d_in[5];
    const float* sage2_Wl     = (const float*)d_in[6];
    const float* sage2_bl     = (const float*)d_in[7];
    const float* sage2_Wr     = (const float*)d_in[8];
    const float* Q_weight     = (const float*)d_in[9];
    const float* text_proj_W  = (const float*)d_in[10];
    const float* text_proj_b  = (const float*)d_in[11];
    const float* cls_W        = (const float*)d_in[12];
    const float* cls_b        = (const float*)d_in[13];
    const int*   edge_index   = (const int*)d_in[14];
    const int*   model_ids    = (const int*)d_in[15];
    const int*   prompt_ids   = (const int*)d_in[16];

    const int E = in_sizes[14] / 2;
    const int B = in_sizes[15];
    const int* src = edge_index;
    const int* dst = edge_index + E;

    // ---- workspace layout (floats) ----
    float* ws  = (float*)d_ws;
    float* x0  = ws;                                   //  950272
    float* h1  = x0 + (size_t)NTRAIN * D0;             // 1048576
    float* x2  = h1 + (size_t)NTRAIN * HID;            //  950272
    float* q   = x2 + (size_t)NTRAIN * D0;             // 3801088 (direct store)
    float* agg = q  + (size_t)B * D0;                  // 1048576
    int*   ib  = (int*)(agg + (size_t)NTRAIN * HID);
    int*   hist    = ib;                               // 4096
    int*   cursor  = ib + 4096;                        // 4096
    int*   row_ptr = ib + 8192;                        // 4097 (pad to 4112)
    float* invdeg  = (float*)(ib + 12304);             // 4096
    int*   csr     = ib + 16400;                       // E

    dim3 blk(256);

    // zero the atomic-accumulated outputs (x0,h1,x2) and the CSR counters
    hipMemsetAsync(ws, 0, ((size_t)NTRAIN * (D0 + HID + D0)) * sizeof(float), stream);
    hipMemsetAsync(ib, 0, 8192 * sizeof(int), stream);

    // ---- CSR build ----
    hist_kernel<<<(E + 255) / 256, blk, 0, stream>>>(dst, hist, E);
    scan_kernel<<<1, 1024, 0, stream>>>(hist, row_ptr, invdeg, E);
    scatter_kernel<<<(E + 255) / 256, blk, 0, stream>>>(src, dst, row_ptr, cursor, csr, E);

    // x0 = P[:4096] @ Wp^T + b   (splitK=4 -> 1024 blocks)
    gemm_fused<<<dim3(4, NTRAIN / BM, 4), blk, 0, stream>>>(
        P_weight, MED, nullptr, model_proj_W,
        nullptr, nullptr, model_proj_b, x0, NTRAIN, D0, MED, MED / 4);

    // layer-1 aggregation (no atomics)
    node_agg<<<NTRAIN, blk, 0, stream>>>(row_ptr, csr, invdeg, x0, agg, D0);

    // h1 = relu(agg @ W1l^T + b1 + x0 @ W1r^T)   (splitK=2)
    gemm_fused<<<dim3(4, NTRAIN / BM, 2), blk, 0, stream>>>(
        agg, D0, nullptr, sage1_Wl,
        x0, sage1_Wr, sage1_bl, h1, NTRAIN, HID, D0, D0 / 2);
    relu_kernel<<<(NTRAIN * HID + 255) / 256, blk, 0, stream>>>(h1, NTRAIN * HID);

    // layer-2 aggregation
    node_agg<<<NTRAIN, blk, 0, stream>>>(row_ptr, csr, invdeg, h1, agg, HID);

    // x2 = agg @ W2l^T + b2 + h1 @ W2r^T   (splitK=2)
    gemm_fused<<<dim3(4, NTRAIN / BM, 2), blk, 0, stream>>>(
        agg, HID, nullptr, sage2_Wl,
        h1, sage2_Wr, sage2_bl, x2, NTRAIN, D0, HID, HID / 2);

    // q = Q[prompt_ids] @ Wt^T + b   (1024 blocks, direct store)
    gemm_fused<<<dim3(4, B / BM, 1), blk, 0, stream>>>(
        Q_weight, TDIM, prompt_ids, text_proj_W,
        nullptr, nullptr, text_proj_b, q, B, D0, TDIM, TDIM);

    // head
    final_head<<<(B * 64 + 255) / 256, blk, 0, stream>>>(
        x2, q, model_ids, cls_W, cls_b, (float*)d_out, B);
}